// Round 2
// baseline (570.380 us; speedup 1.0000x reference)
//
#include <hip/hip_runtime.h>
#include <stdint.h>

#define F0    2048      // base input features (= GEMM K)
#define EROWS 512       // embed rows per level
#define NOUT  2048      // output features (= GEMM N)
#define MROWS 8192      // batch (= GEMM M)
#define NB    512       // blocks in fused prep kernel (2 per CU, co-resident)

typedef __attribute__((ext_vector_type(8))) short bf16x8;
typedef __attribute__((ext_vector_type(4))) float f32x4;
typedef __attribute__((ext_vector_type(8))) unsigned short u16x8;

typedef const __attribute__((address_space(1))) unsigned char ga_t;
typedef __attribute__((address_space(3))) unsigned char lds_t;

__device__ __forceinline__ void async_load16(const void* g, void* l) {
  __builtin_amdgcn_global_load_lds((ga_t*)g, (lds_t*)l, 16, 0, 0);
}

__device__ __forceinline__ unsigned short f2bf(float f) {
  unsigned int u = __builtin_bit_cast(unsigned int, f);
  u += 0x7fffu + ((u >> 16) & 1u);   // round-to-nearest-even
  return (unsigned short)(u >> 16);
}

// Device-scope grid barrier: monotonic counter, zeroed by a memset node
// before launch. All NB blocks are co-resident (2/CU by launch bounds).
__device__ __forceinline__ void gbar(int* cnt, int target) {
  __syncthreads();
  if (threadIdx.x == 0) {
    __threadfence();   // make this block's global writes device-visible
    __hip_atomic_fetch_add(cnt, 1, __ATOMIC_ACQ_REL, __HIP_MEMORY_SCOPE_AGENT);
    while (__hip_atomic_load(cnt, __ATOMIC_ACQUIRE, __HIP_MEMORY_SCOPE_AGENT) < target)
      __builtin_amdgcn_s_sleep(1);
    __threadfence();
  }
  __syncthreads();
}

// Build one dense row (over x-space) of a sparse COO weight into LDS acc.
// Indirect cols (c >= F0) AXPY the previously-expanded dense row Dsrc[c-F0].
__device__ __forceinline__ void build_row(
    const int* __restrict__ rows, const int* __restrict__ cols,
    const float* __restrict__ vals, int nnz, int r,
    const float* __restrict__ Dsrc,
    float* acc, int* s_col, float* s_val, int* s_cnt)
{
  const int tid = threadIdx.x;
  for (int j = tid; j < F0; j += 256) acc[j] = 0.f;
  if (tid == 0) *s_cnt = 0;
  __syncthreads();

  for (int k = tid; k < nnz; k += 256) {
    if (rows[k] == r) {
      int i = atomicAdd(s_cnt, 1);
      if (i < 512) { s_col[i] = cols[k]; s_val[i] = vals[k]; }
    }
  }
  __syncthreads();
  int cnt = *s_cnt; if (cnt > 512) cnt = 512;

  // direct entries (duplicates possible -> LDS atomics)
  for (int i = tid; i < cnt; i += 256) {
    int c = s_col[i];
    if (c < F0) atomicAdd(&acc[c], s_val[i]);
  }
  __syncthreads();

  // indirect entries -> block-wide vectorized AXPY
  for (int i = 0; i < cnt; ++i) {
    int c = s_col[i];
    if (c >= F0) {
      const float4* s4 = (const float4*)(Dsrc + (size_t)(c - F0) * F0);
      float4* a4 = (float4*)acc;
      float v = s_val[i];
      for (int j = tid; j < F0 / 4; j += 256) {
        float4 sv = s4[j]; float4 av = a4[j];
        av.x += v * sv.x; av.y += v * sv.y;
        av.z += v * sv.z; av.w += v * sv.w;
        a4[j] = av;
      }
    }
  }
  __syncthreads();
}

// ---------------------------------------------------------------------------
// Fused prep: E0 -> bar -> E1 -> bar -> E2 -> bar -> EM(bf16) -> x cast
// ---------------------------------------------------------------------------
__global__ __launch_bounds__(256, 2) void prep_kernel(
    const float* __restrict__ x,
    const int* __restrict__ er0, const int* __restrict__ ec0, const float* __restrict__ ev0, int n0,
    const int* __restrict__ er1, const int* __restrict__ ec1, const float* __restrict__ ev1, int n1,
    const int* __restrict__ er2, const int* __restrict__ ec2, const float* __restrict__ ev2, int n2,
    const int* __restrict__ mr,  const int* __restrict__ mc,  const float* __restrict__ mv,  int nm,
    float* __restrict__ D, unsigned short* __restrict__ Mb,
    unsigned short* __restrict__ Ab, int* __restrict__ bar)
{
  __shared__ float acc[F0];
  __shared__ int   s_col[512];
  __shared__ float s_val[512];
  __shared__ int   s_cnt;
  const int b = blockIdx.x;
  const int tid = threadIdx.x;

  // level 0 (all cols direct; Dsrc unused)
  build_row(er0, ec0, ev0, n0, b, D, acc, s_col, s_val, &s_cnt);
  { float4* dst = (float4*)(D + (size_t)b * F0);
    const float4* a4 = (const float4*)acc;
    for (int j = tid; j < F0 / 4; j += 256) dst[j] = a4[j]; }
  gbar(bar, NB * 1);

  // level 1 (indirect cols hit D0)
  build_row(er1, ec1, ev1, n1, b, D, acc, s_col, s_val, &s_cnt);
  { float4* dst = (float4*)(D + (size_t)(EROWS + b) * F0);
    const float4* a4 = (const float4*)acc;
    for (int j = tid; j < F0 / 4; j += 256) dst[j] = a4[j]; }
  gbar(bar, NB * 2);

  // level 2 (indirect cols hit D0/D1)
  build_row(er2, ec2, ev2, n2, b, D, acc, s_col, s_val, &s_cnt);
  { float4* dst = (float4*)(D + (size_t)(2 * EROWS + b) * F0);
    const float4* a4 = (const float4*)acc;
    for (int j = tid; j < F0 / 4; j += 256) dst[j] = a4[j]; }
  gbar(bar, NB * 3);

  // MAIN: 4 rows per block, write bf16 directly
  for (int rr = 0; rr < 4; ++rr) {
    int r = b * 4 + rr;
    build_row(mr, mc, mv, nm, r, D, acc, s_col, s_val, &s_cnt);
    u16x8* dst = (u16x8*)(Mb + (size_t)r * F0);
    for (int j = tid; j < F0 / 8; j += 256) {
      u16x8 o;
#pragma unroll
      for (int e = 0; e < 8; ++e) o[e] = f2bf(acc[j * 8 + e]);
      dst[j] = o;
    }
    __syncthreads();   // acc reused (zeroed) next iteration
  }

  // x -> bf16 cast: 16M elems = 2M vec8 over 131072 threads = 16 iters exact
  const float4* xp = (const float4*)x;
  u16x8* ap = (u16x8*)Ab;
  const int gt = b * 256 + tid;
  for (int it = 0; it < 16; ++it) {
    int i = it * (NB * 256) + gt;
    float4 a = xp[i * 2], c = xp[i * 2 + 1];
    u16x8 o;
    o[0] = f2bf(a.x); o[1] = f2bf(a.y); o[2] = f2bf(a.z); o[3] = f2bf(a.w);
    o[4] = f2bf(c.x); o[5] = f2bf(c.y); o[6] = f2bf(c.z); o[7] = f2bf(c.w);
    ap[i] = o;
  }
}

// ---------------------------------------------------------------------------
// C[m,n] = sum_k A[m,k] * B[n,k]   (A: MROWSxK bf16, B: NOUTxK bf16, C fp32)
// 128x128 tile, BK=64, 4 waves (2x2 of 64x64), global_load_lds width=16,
// XOR-swizzled LDS (chunk c stored at slot c ^ (row&7)) to balance banks.
// ---------------------------------------------------------------------------
__global__ __launch_bounds__(256) void gemm_bt_kernel(
    const unsigned short* __restrict__ A, const unsigned short* __restrict__ B,
    float* __restrict__ C)
{
  constexpr int K = F0;
  constexpr int N = NOUT;
  __shared__ __align__(16) unsigned short sA[128 * 64];
  __shared__ __align__(16) unsigned short sB[128 * 64];

  const int tid  = threadIdx.x;
  const int lane = tid & 63;
  const int w    = tid >> 6;
  const int wm   = (w & 1) * 64;
  const int wn   = (w >> 1) * 64;
  const int mm   = lane & 15;
  const int g    = lane >> 4;
  const int bm   = blockIdx.y;
  const int bn   = blockIdx.x;

  const unsigned short* Ag = A + (size_t)bm * 128 * K;
  const unsigned short* Bg = B + (size_t)bn * 128 * K;

  int su[4], srow[4], scg[4];
  for (int i = 0; i < 4; ++i) {
    int u = i * 256 + tid;
    su[i]   = u;
    srow[i] = u >> 3;
    scg[i]  = (u & 7) ^ ((u >> 3) & 7);
  }

  f32x4 acc[4][4];
  for (int a = 0; a < 4; ++a)
    for (int b2 = 0; b2 < 4; ++b2) acc[a][b2] = (f32x4)0.f;

  for (int k0 = 0; k0 < K; k0 += 64) {
    for (int i = 0; i < 4; ++i) {
      async_load16(Ag + (size_t)srow[i] * K + k0 + scg[i] * 8, sA + su[i] * 8);
      async_load16(Bg + (size_t)srow[i] * K + k0 + scg[i] * 8, sB + su[i] * 8);
    }
    __syncthreads();

    for (int ks = 0; ks < 2; ++ks) {
      bf16x8 af[4], bf[4];
      for (int t = 0; t < 4; ++t) {
        int mrow = wm + t * 16 + mm;
        int sa   = (ks * 4 + g) ^ (mrow & 7);
        af[t] = *(const bf16x8*)(sA + mrow * 64 + sa * 8);
        int nrow = wn + t * 16 + mm;
        int sb   = (ks * 4 + g) ^ (nrow & 7);
        bf[t] = *(const bf16x8*)(sB + nrow * 64 + sb * 8);
      }
      for (int tm = 0; tm < 4; ++tm)
        for (int tn = 0; tn < 4; ++tn)
          acc[tm][tn] = __builtin_amdgcn_mfma_f32_16x16x32_bf16(
              af[tm], bf[tn], acc[tm][tn], 0, 0, 0);
    }
    __syncthreads();
  }

  for (int tm = 0; tm < 4; ++tm) {
    int rowb = bm * 128 + wm + tm * 16 + g * 4;
    for (int tn = 0; tn < 4; ++tn) {
      int col = bn * 128 + wn + tn * 16 + mm;
      for (int r = 0; r < 4; ++r)
        C[(size_t)(rowb + r) * N + col] = acc[tm][tn][r];
    }
  }
}

// ---------------------------------------------------------------------------
extern "C" void kernel_launch(void* const* d_in, const int* in_sizes, int n_in,
                              void* d_out, int out_size, void* d_ws, size_t ws_size,
                              hipStream_t stream)
{
  const float* x   = (const float*)d_in[0];
  const int*   er0 = (const int*)d_in[1];
  const int*   ec0 = (const int*)d_in[2];
  const float* ev0 = (const float*)d_in[3];
  const int*   er1 = (const int*)d_in[4];
  const int*   ec1 = (const int*)d_in[5];
  const float* ev1 = (const float*)d_in[6];
  const int*   er2 = (const int*)d_in[7];
  const int*   ec2 = (const int*)d_in[8];
  const float* ev2 = (const float*)d_in[9];
  const int*   mr  = (const int*)d_in[10];
  const int*   mc  = (const int*)d_in[11];
  const float* mv  = (const float*)d_in[12];
  const int nnz_e0 = in_sizes[1];
  const int nnz_e1 = in_sizes[4];
  const int nnz_e2 = in_sizes[7];
  const int nnz_m  = in_sizes[10];

  // workspace: [bar(256B pad)] [D 12MB fp32] [Mb 8MB bf16] [Ab 32MB bf16]
  int* bar = (int*)d_ws;
  float* D = (float*)((char*)d_ws + 256);
  unsigned short* Mb = (unsigned short*)(D + (size_t)3 * EROWS * F0);
  unsigned short* Ab = Mb + (size_t)NOUT * F0;

  hipMemsetAsync(d_ws, 0, 4, stream);   // zero barrier counter (memset node)

  hipLaunchKernelGGL(prep_kernel, dim3(NB), dim3(256), 0, stream,
                     x,
                     er0, ec0, ev0, nnz_e0,
                     er1, ec1, ev1, nnz_e1,
                     er2, ec2, ev2, nnz_e2,
                     mr,  mc,  mv,  nnz_m,
                     D, Mb, Ab, bar);

  hipLaunchKernelGGL(gemm_bt_kernel, dim3(NOUT / 128, MROWS / 128), dim3(256),
                     0, stream, Ab, Mb, (float*)d_out);
}

// Round 3
// 309.164 us; speedup vs baseline: 1.8449x; 1.8449x over previous
//
#include <hip/hip_runtime.h>
#include <stdint.h>

#define F0    2048      // base input features (= GEMM K)
#define EROWS 512       // embed rows per level
#define NOUT  2048      // output features (= GEMM N)
#define MROWS 8192      // batch (= GEMM M)

typedef __attribute__((ext_vector_type(8))) short bf16x8;
typedef __attribute__((ext_vector_type(4))) float f32x4;
typedef __attribute__((ext_vector_type(8))) unsigned short u16x8;

typedef const __attribute__((address_space(1))) unsigned char ga_t;
typedef __attribute__((address_space(3))) unsigned char lds_t;

__device__ __forceinline__ void async_load16(const void* g, void* l) {
  __builtin_amdgcn_global_load_lds((ga_t*)g, (lds_t*)l, 16, 0, 0);
}

__device__ __forceinline__ unsigned short f2bf(float f) {
  unsigned int u = __builtin_bit_cast(unsigned int, f);
  u += 0x7fffu + ((u >> 16) & 1u);   // round-to-nearest-even
  return (unsigned short)(u >> 16);
}

// ---------------------------------------------------------------------------
// Blocks 0..3: CSR-ize weight b (LDS histogram -> scan -> scatter).
// Blocks 4..2051: x -> bf16 cast (1024 vec8 per block).
// ---------------------------------------------------------------------------
__global__ __launch_bounds__(256) void csr_cast_kernel(
    const int* __restrict__ r0, const int* __restrict__ c0, const float* __restrict__ v0, int n0,
    const int* __restrict__ r1, const int* __restrict__ c1, const float* __restrict__ v1, int n1,
    const int* __restrict__ r2, const int* __restrict__ c2, const float* __restrict__ v2, int n2,
    const int* __restrict__ rm, const int* __restrict__ cm, const float* __restrict__ vm, int nm,
    int* __restrict__ rp_all, int* __restrict__ cc_all, float* __restrict__ cv_all,
    const float* __restrict__ x, unsigned short* __restrict__ Ab)
{
  const int b = blockIdx.x;
  const int tid = threadIdx.x;

  if (b >= 4) {
    // ---- x cast: 16,777,216 floats = 2,097,152 vec8; 2048 blocks x 1024 vec8
    const int cb = b - 4;
    const float4* xp = (const float4*)x;
    u16x8* ap = (u16x8*)Ab;
#pragma unroll
    for (int it = 0; it < 4; ++it) {
      int i = cb * 1024 + it * 256 + tid;
      float4 a = xp[2 * i], c = xp[2 * i + 1];
      u16x8 o;
      o[0] = f2bf(a.x); o[1] = f2bf(a.y); o[2] = f2bf(a.z); o[3] = f2bf(a.w);
      o[4] = f2bf(c.x); o[5] = f2bf(c.y); o[6] = f2bf(c.z); o[7] = f2bf(c.w);
      ap[i] = o;
    }
    return;
  }

  // ---- CSR-ize one weight
  const int* rows; const int* cols; const float* vals; int nnz, nrows;
  if      (b == 0) { rows = r0; cols = c0; vals = v0; nnz = n0; nrows = EROWS; }
  else if (b == 1) { rows = r1; cols = c1; vals = v1; nnz = n1; nrows = EROWS; }
  else if (b == 2) { rows = r2; cols = c2; vals = v2; nnz = n2; nrows = EROWS; }
  else             { rows = rm; cols = cm; vals = vm; nnz = nm; nrows = NOUT; }
  int* rp  = rp_all + b * 4096;          // row_ptr slot (padded)
  int* cc  = cc_all + b * 8192;          // per-weight nnz region (main=16384 fits: slot 3 is last)
  float* cv = cv_all + b * 8192;

  __shared__ int hist[NOUT + 1];
  __shared__ int tsum[256];

  for (int i = tid; i < nrows; i += 256) hist[i] = 0;
  __syncthreads();
  for (int k = tid; k < nnz; k += 256) atomicAdd(&hist[rows[k]], 1);
  __syncthreads();

  // exclusive scan over nrows bins: per-thread serial + thread0 combine
  const int per = nrows / 256;           // 2 or 8
  const int base = tid * per;
  int sum = 0;
  for (int i = 0; i < per; ++i) sum += hist[base + i];
  tsum[tid] = sum;
  __syncthreads();
  if (tid == 0) {
    int run = 0;
    for (int i = 0; i < 256; ++i) { int t = tsum[i]; tsum[i] = run; run += t; }
  }
  __syncthreads();
  int run = tsum[tid];
  for (int i = 0; i < per; ++i) { int h = hist[base + i]; hist[base + i] = run; run += h; }
  __syncthreads();

  for (int i = tid; i < nrows; i += 256) rp[i] = hist[i];
  if (tid == 0) rp[nrows] = nnz;
  __syncthreads();

  // scatter (hist doubles as running write cursor per row)
  for (int k = tid; k < nnz; k += 256) {
    int pos = atomicAdd(&hist[rows[k]], 1);
    cc[pos] = cols[k];
    cv[pos] = vals[k];
  }
}

// ---------------------------------------------------------------------------
// One block per dense output row. Direct entries (c<F0) -> LDS atomics;
// indirect (c>=F0) -> register AXPY with prior dense row Dsrc[c-F0].
// Each thread owns 8 consecutive columns. BF16OUT writes u16x8 directly.
// ---------------------------------------------------------------------------
template <bool BF16OUT>
__global__ __launch_bounds__(256) void expand_csr_kernel(
    const int* __restrict__ rp, const int* __restrict__ cc,
    const float* __restrict__ cv, const float* __restrict__ Dsrc,
    void* __restrict__ out)
{
  const int r = blockIdx.x;
  const int tid = threadIdx.x;
  __shared__ float acc[F0];
  __shared__ int   icol[128];
  __shared__ float ival[128];
  __shared__ int   icnt;

  float4* a4 = (float4*)acc;
  a4[tid * 2]     = (float4){0.f, 0.f, 0.f, 0.f};
  a4[tid * 2 + 1] = (float4){0.f, 0.f, 0.f, 0.f};
  if (tid == 0) icnt = 0;
  __syncthreads();

  const int s = rp[r], e = rp[r + 1];
  for (int i = s + tid; i < e; i += 256) {
    int c = cc[i]; float v = cv[i];
    if (c < F0) atomicAdd(&acc[c], v);
    else { int p = atomicAdd(&icnt, 1); if (p < 128) { icol[p] = c - F0; ival[p] = v; } }
  }
  __syncthreads();
  int n = icnt; if (n > 128) n = 128;

  float4 q0 = a4[tid * 2], q1 = a4[tid * 2 + 1];
  for (int j = 0; j < n; ++j) {
    const float4* src = (const float4*)(Dsrc + (size_t)icol[j] * F0) + tid * 2;
    float v = ival[j];
    float4 s0 = src[0], s1 = src[1];
    q0.x += v * s0.x; q0.y += v * s0.y; q0.z += v * s0.z; q0.w += v * s0.w;
    q1.x += v * s1.x; q1.y += v * s1.y; q1.z += v * s1.z; q1.w += v * s1.w;
  }

  if (BF16OUT) {
    u16x8 o;
    o[0] = f2bf(q0.x); o[1] = f2bf(q0.y); o[2] = f2bf(q0.z); o[3] = f2bf(q0.w);
    o[4] = f2bf(q1.x); o[5] = f2bf(q1.y); o[6] = f2bf(q1.z); o[7] = f2bf(q1.w);
    ((u16x8*)out)[(size_t)r * 256 + tid] = o;
  } else {
    float4* dst = (float4*)out + (size_t)r * 512 + tid * 2;
    dst[0] = q0; dst[1] = q1;
  }
}

// ---------------------------------------------------------------------------
// C[m,n] = sum_k A[m,k] * B[n,k]   (A: MROWSxK bf16, B: NOUTxK bf16, C fp32)
// 128x128 tile, BK=64, 4 waves (2x2 of 64x64), global_load_lds width=16,
// XOR-swizzled LDS.
// ---------------------------------------------------------------------------
__global__ __launch_bounds__(256) void gemm_bt_kernel(
    const unsigned short* __restrict__ A, const unsigned short* __restrict__ B,
    float* __restrict__ C)
{
  constexpr int K = F0;
  constexpr int N = NOUT;
  __shared__ __align__(16) unsigned short sA[128 * 64];
  __shared__ __align__(16) unsigned short sB[128 * 64];

  const int tid  = threadIdx.x;
  const int lane = tid & 63;
  const int w    = tid >> 6;
  const int wm   = (w & 1) * 64;
  const int wn   = (w >> 1) * 64;
  const int mm   = lane & 15;
  const int g    = lane >> 4;
  const int bm   = blockIdx.y;
  const int bn   = blockIdx.x;

  const unsigned short* Ag = A + (size_t)bm * 128 * K;
  const unsigned short* Bg = B + (size_t)bn * 128 * K;

  int su[4], srow[4], scg[4];
  for (int i = 0; i < 4; ++i) {
    int u = i * 256 + tid;
    su[i]   = u;
    srow[i] = u >> 3;
    scg[i]  = (u & 7) ^ ((u >> 3) & 7);
  }

  f32x4 acc[4][4];
  for (int a = 0; a < 4; ++a)
    for (int b2 = 0; b2 < 4; ++b2) acc[a][b2] = (f32x4)0.f;

  for (int k0 = 0; k0 < K; k0 += 64) {
    for (int i = 0; i < 4; ++i) {
      async_load16(Ag + (size_t)srow[i] * K + k0 + scg[i] * 8, sA + su[i] * 8);
      async_load16(Bg + (size_t)srow[i] * K + k0 + scg[i] * 8, sB + su[i] * 8);
    }
    __syncthreads();

    for (int ks = 0; ks < 2; ++ks) {
      bf16x8 af[4], bf[4];
      for (int t = 0; t < 4; ++t) {
        int mrow = wm + t * 16 + mm;
        int sa   = (ks * 4 + g) ^ (mrow & 7);
        af[t] = *(const bf16x8*)(sA + mrow * 64 + sa * 8);
        int nrow = wn + t * 16 + mm;
        int sb   = (ks * 4 + g) ^ (nrow & 7);
        bf[t] = *(const bf16x8*)(sB + nrow * 64 + sb * 8);
      }
      for (int tm = 0; tm < 4; ++tm)
        for (int tn = 0; tn < 4; ++tn)
          acc[tm][tn] = __builtin_amdgcn_mfma_f32_16x16x32_bf16(
              af[tm], bf[tn], acc[tm][tn], 0, 0, 0);
    }
    __syncthreads();
  }

  for (int tm = 0; tm < 4; ++tm) {
    int rowb = bm * 128 + wm + tm * 16 + g * 4;
    for (int tn = 0; tn < 4; ++tn) {
      int col = bn * 128 + wn + tn * 16 + mm;
      for (int r = 0; r < 4; ++r)
        C[(size_t)(rowb + r) * N + col] = acc[tm][tn][r];
    }
  }
}

// ---------------------------------------------------------------------------
extern "C" void kernel_launch(void* const* d_in, const int* in_sizes, int n_in,
                              void* d_out, int out_size, void* d_ws, size_t ws_size,
                              hipStream_t stream)
{
  const float* x   = (const float*)d_in[0];
  const int*   er0 = (const int*)d_in[1];
  const int*   ec0 = (const int*)d_in[2];
  const float* ev0 = (const float*)d_in[3];
  const int*   er1 = (const int*)d_in[4];
  const int*   ec1 = (const int*)d_in[5];
  const float* ev1 = (const float*)d_in[6];
  const int*   er2 = (const int*)d_in[7];
  const int*   ec2 = (const int*)d_in[8];
  const float* ev2 = (const float*)d_in[9];
  const int*   mr  = (const int*)d_in[10];
  const int*   mc  = (const int*)d_in[11];
  const float* mv  = (const float*)d_in[12];
  const int nnz_e0 = in_sizes[1];
  const int nnz_e1 = in_sizes[4];
  const int nnz_e2 = in_sizes[7];
  const int nnz_m  = in_sizes[10];

  // workspace layout:
  // rp_all: 4 x 4096 ints (64 KB) | cc_all: 4 x 8192 ints... main uses 16384,
  // so give cc/cv 32768-entry regions each with main at slot 3 (8192*3..+16384).
  int*   rp_all = (int*)d_ws;                              // 4*4096 ints
  int*   cc_all = rp_all + 4 * 4096;                       // 40960 ints used
  float* cv_all = (float*)(cc_all + 48 * 1024);            // 40960 floats used
  float* D      = (float*)(cv_all + 48 * 1024);            // [3*EROWS][F0] fp32 (12 MB)
  unsigned short* Mb = (unsigned short*)(D + (size_t)3 * EROWS * F0);  // 8 MB
  unsigned short* Ab = Mb + (size_t)NOUT * F0;             // 32 MB

  // 1) CSR-ize all four weights + cast x to bf16 (independent work, one node)
  hipLaunchKernelGGL(csr_cast_kernel, dim3(4 + 2048), dim3(256), 0, stream,
                     er0, ec0, ev0, nnz_e0,
                     er1, ec1, ev1, nnz_e1,
                     er2, ec2, ev2, nnz_e2,
                     mr,  mc,  mv,  nnz_m,
                     rp_all, cc_all, cv_all, x, Ab);

  // 2) expand chain (each launch depends on the previous -> stream order)
  hipLaunchKernelGGL((expand_csr_kernel<false>), dim3(EROWS), dim3(256), 0, stream,
                     rp_all + 0 * 4096, cc_all + 0 * 8192, cv_all + 0 * 8192,
                     D, (void*)D);
  hipLaunchKernelGGL((expand_csr_kernel<false>), dim3(EROWS), dim3(256), 0, stream,
                     rp_all + 1 * 4096, cc_all + 1 * 8192, cv_all + 1 * 8192,
                     D, (void*)(D + (size_t)EROWS * F0));
  hipLaunchKernelGGL((expand_csr_kernel<false>), dim3(EROWS), dim3(256), 0, stream,
                     rp_all + 2 * 4096, cc_all + 2 * 8192, cv_all + 2 * 8192,
                     D, (void*)(D + (size_t)2 * EROWS * F0));
  hipLaunchKernelGGL((expand_csr_kernel<true>), dim3(NOUT), dim3(256), 0, stream,
                     rp_all + 3 * 4096, cc_all + 3 * 8192, cv_all + 3 * 8192,
                     D, (void*)Mb);

  // 3) out = x @ M^T
  hipLaunchKernelGGL(gemm_bt_kernel, dim3(NOUT / 128, MROWS / 128), dim3(256),
                     0, stream, Ab, Mb, (float*)d_out);
}

// Round 4
// 262.362 us; speedup vs baseline: 2.1740x; 1.1784x over previous
//
#include <hip/hip_runtime.h>
#include <stdint.h>

#define F0    2048      // base input features (= GEMM K)
#define EROWS 512       // embed rows per level
#define NOUT  2048      // output features (= GEMM N)
#define MROWS 8192      // batch (= GEMM M)

typedef __attribute__((ext_vector_type(8))) short bf16x8;
typedef __attribute__((ext_vector_type(4))) float f32x4;
typedef __attribute__((ext_vector_type(8))) unsigned short u16x8;

typedef const __attribute__((address_space(1))) unsigned char ga_t;
typedef __attribute__((address_space(3))) unsigned char lds_t;

__device__ __forceinline__ void async_load16(const void* g, void* l) {
  __builtin_amdgcn_global_load_lds((ga_t*)g, (lds_t*)l, 16, 0, 0);
}

__device__ __forceinline__ unsigned short f2bf(float f) {
  unsigned int u = __builtin_bit_cast(unsigned int, f);
  u += 0x7fffu + ((u >> 16) & 1u);   // round-to-nearest-even
  return (unsigned short)(u >> 16);
}

// ---------------------------------------------------------------------------
// Blocks 0..3: CSR-ize weight b. Latency-optimized: 8 contiguous entries per
// thread per round (int4 x2 loads), parallel scan (no thread0 serial loop).
// Blocks 4..2051: x -> bf16 cast (1024 vec8 per block).
// ---------------------------------------------------------------------------
__global__ __launch_bounds__(256) void csr_cast_kernel(
    const int* __restrict__ r0, const int* __restrict__ c0, const float* __restrict__ v0, int n0,
    const int* __restrict__ r1, const int* __restrict__ c1, const float* __restrict__ v1, int n1,
    const int* __restrict__ r2, const int* __restrict__ c2, const float* __restrict__ v2, int n2,
    const int* __restrict__ rm, const int* __restrict__ cm, const float* __restrict__ vm, int nm,
    int* __restrict__ rp_all, int* __restrict__ cc_all, float* __restrict__ cv_all,
    const float* __restrict__ x, unsigned short* __restrict__ Ab)
{
  const int b = blockIdx.x;
  const int tid = threadIdx.x;

  if (b >= 4) {
    // ---- x cast: 16,777,216 floats = 2,097,152 vec8; 2048 blocks x 1024 vec8
    const int cb = b - 4;
    const float4* xp = (const float4*)x;
    u16x8* ap = (u16x8*)Ab;
#pragma unroll
    for (int it = 0; it < 4; ++it) {
      int i = cb * 1024 + it * 256 + tid;
      float4 a = xp[2 * i], c = xp[2 * i + 1];
      u16x8 o;
      o[0] = f2bf(a.x); o[1] = f2bf(a.y); o[2] = f2bf(a.z); o[3] = f2bf(a.w);
      o[4] = f2bf(c.x); o[5] = f2bf(c.y); o[6] = f2bf(c.z); o[7] = f2bf(c.w);
      ap[i] = o;
    }
    return;
  }

  // ---- CSR-ize one weight
  const int* rows; const int* cols; const float* vals; int nnz, nrows;
  if      (b == 0) { rows = r0; cols = c0; vals = v0; nnz = n0; nrows = EROWS; }
  else if (b == 1) { rows = r1; cols = c1; vals = v1; nnz = n1; nrows = EROWS; }
  else if (b == 2) { rows = r2; cols = c2; vals = v2; nnz = n2; nrows = EROWS; }
  else             { rows = rm; cols = cm; vals = vm; nnz = nm; nrows = NOUT; }
  int* rp  = rp_all + b * 4096;
  int* cc  = cc_all + b * 8192;          // main (b=3) spills into 16384 entries: region sized for it
  float* cv = cv_all + b * 8192;

  __shared__ int hist[NOUT + 1];
  __shared__ int tsum[256];

  for (int i = tid; i < nrows; i += 256) hist[i] = 0;
  __syncthreads();

  // --- histogram: 8 contiguous entries per thread per round
  int k0 = 0;
  for (; k0 + 2048 <= nnz; k0 += 2048) {
    const int kk = k0 + tid * 8;
    int4 ra = *(const int4*)(rows + kk);
    int4 rb = *(const int4*)(rows + kk + 4);
    atomicAdd(&hist[ra.x], 1); atomicAdd(&hist[ra.y], 1);
    atomicAdd(&hist[ra.z], 1); atomicAdd(&hist[ra.w], 1);
    atomicAdd(&hist[rb.x], 1); atomicAdd(&hist[rb.y], 1);
    atomicAdd(&hist[rb.z], 1); atomicAdd(&hist[rb.w], 1);
  }
  for (int k = k0 + tid; k < nnz; k += 256) atomicAdd(&hist[rows[k]], 1);
  __syncthreads();

  // --- exclusive scan: per-thread partials + parallel Hillis-Steele on 256
  const int per = nrows >> 8;            // 2 or 8
  const int base = tid * per;
  int sum = 0;
  for (int i = 0; i < per; ++i) sum += hist[base + i];
  tsum[tid] = sum;
  __syncthreads();
  for (int off = 1; off < 256; off <<= 1) {
    int add = (tid >= off) ? tsum[tid - off] : 0;
    __syncthreads();
    tsum[tid] += add;
    __syncthreads();
  }
  int run = (tid == 0) ? 0 : tsum[tid - 1];
  for (int i = 0; i < per; ++i) { int h = hist[base + i]; hist[base + i] = run; run += h; }
  __syncthreads();

  for (int i = tid; i < nrows; i += 256) rp[i] = hist[i];
  if (tid == 0) rp[nrows] = nnz;
  __syncthreads();

  // --- scatter: 8 contiguous entries per thread per round (hist = cursors)
  k0 = 0;
  for (; k0 + 2048 <= nnz; k0 += 2048) {
    const int kk = k0 + tid * 8;
    int4   ra = *(const int4*)(rows + kk);
    int4   rb = *(const int4*)(rows + kk + 4);
    int4   ca = *(const int4*)(cols + kk);
    int4   cb2 = *(const int4*)(cols + kk + 4);
    float4 va = *(const float4*)(vals + kk);
    float4 vb = *(const float4*)(vals + kk + 4);
    int p;
    p = atomicAdd(&hist[ra.x], 1); cc[p] = ca.x;  cv[p] = va.x;
    p = atomicAdd(&hist[ra.y], 1); cc[p] = ca.y;  cv[p] = va.y;
    p = atomicAdd(&hist[ra.z], 1); cc[p] = ca.z;  cv[p] = va.z;
    p = atomicAdd(&hist[ra.w], 1); cc[p] = ca.w;  cv[p] = va.w;
    p = atomicAdd(&hist[rb.x], 1); cc[p] = cb2.x; cv[p] = vb.x;
    p = atomicAdd(&hist[rb.y], 1); cc[p] = cb2.y; cv[p] = vb.y;
    p = atomicAdd(&hist[rb.z], 1); cc[p] = cb2.z; cv[p] = vb.z;
    p = atomicAdd(&hist[rb.w], 1); cc[p] = cb2.w; cv[p] = vb.w;
  }
  for (int k = k0 + tid; k < nnz; k += 256) {
    int p = atomicAdd(&hist[rows[k]], 1);
    cc[p] = cols[k]; cv[p] = vals[k];
  }
}

// ---------------------------------------------------------------------------
// One block per dense output row. Direct entries (c<F0) -> LDS atomics;
// indirect (c>=F0) -> register AXPY with prior dense row Dsrc[c-F0].
// Each thread owns 8 consecutive columns. BF16OUT writes u16x8 directly.
// ---------------------------------------------------------------------------
template <bool BF16OUT>
__global__ __launch_bounds__(256) void expand_csr_kernel(
    const int* __restrict__ rp, const int* __restrict__ cc,
    const float* __restrict__ cv, const float* __restrict__ Dsrc,
    void* __restrict__ out)
{
  const int r = blockIdx.x;
  const int tid = threadIdx.x;
  __shared__ float acc[F0];
  __shared__ int   icol[128];
  __shared__ float ival[128];
  __shared__ int   icnt;

  float4* a4 = (float4*)acc;
  a4[tid * 2]     = (float4){0.f, 0.f, 0.f, 0.f};
  a4[tid * 2 + 1] = (float4){0.f, 0.f, 0.f, 0.f};
  if (tid == 0) icnt = 0;
  __syncthreads();

  const int s = rp[r], e = rp[r + 1];
  for (int i = s + tid; i < e; i += 256) {
    int c = cc[i]; float v = cv[i];
    if (c < F0) atomicAdd(&acc[c], v);
    else { int p = atomicAdd(&icnt, 1); if (p < 128) { icol[p] = c - F0; ival[p] = v; } }
  }
  __syncthreads();
  int n = icnt; if (n > 128) n = 128;

  float4 q0 = a4[tid * 2], q1 = a4[tid * 2 + 1];
  for (int j = 0; j < n; ++j) {
    const float4* src = (const float4*)(Dsrc + (size_t)icol[j] * F0) + tid * 2;
    float v = ival[j];
    float4 s0 = src[0], s1 = src[1];
    q0.x += v * s0.x; q0.y += v * s0.y; q0.z += v * s0.z; q0.w += v * s0.w;
    q1.x += v * s1.x; q1.y += v * s1.y; q1.z += v * s1.z; q1.w += v * s1.w;
  }

  if (BF16OUT) {
    u16x8 o;
    o[0] = f2bf(q0.x); o[1] = f2bf(q0.y); o[2] = f2bf(q0.z); o[3] = f2bf(q0.w);
    o[4] = f2bf(q1.x); o[5] = f2bf(q1.y); o[6] = f2bf(q1.z); o[7] = f2bf(q1.w);
    ((u16x8*)out)[(size_t)r * 256 + tid] = o;
  } else {
    float4* dst = (float4*)out + (size_t)r * 512 + tid * 2;
    dst[0] = q0; dst[1] = q1;
  }
}

// ---------------------------------------------------------------------------
// C[m,n] = sum_k A[m,k] * B[n,k]   (A: MROWSxK bf16, B: NOUTxK bf16, C fp32)
// 128x128 tile, BK=64, 4 waves (2x2 of 64x64), global_load_lds width=16,
// XOR-swizzled LDS.
// ---------------------------------------------------------------------------
__global__ __launch_bounds__(256) void gemm_bt_kernel(
    const unsigned short* __restrict__ A, const unsigned short* __restrict__ B,
    float* __restrict__ C)
{
  constexpr int K = F0;
  constexpr int N = NOUT;
  __shared__ __align__(16) unsigned short sA[128 * 64];
  __shared__ __align__(16) unsigned short sB[128 * 64];

  const int tid  = threadIdx.x;
  const int lane = tid & 63;
  const int w    = tid >> 6;
  const int wm   = (w & 1) * 64;
  const int wn   = (w >> 1) * 64;
  const int mm   = lane & 15;
  const int g    = lane >> 4;
  const int bm   = blockIdx.y;
  const int bn   = blockIdx.x;

  const unsigned short* Ag = A + (size_t)bm * 128 * K;
  const unsigned short* Bg = B + (size_t)bn * 128 * K;

  int su[4], srow[4], scg[4];
  for (int i = 0; i < 4; ++i) {
    int u = i * 256 + tid;
    su[i]   = u;
    srow[i] = u >> 3;
    scg[i]  = (u & 7) ^ ((u >> 3) & 7);
  }

  f32x4 acc[4][4];
  for (int a = 0; a < 4; ++a)
    for (int b2 = 0; b2 < 4; ++b2) acc[a][b2] = (f32x4)0.f;

  for (int k0 = 0; k0 < K; k0 += 64) {
    for (int i = 0; i < 4; ++i) {
      async_load16(Ag + (size_t)srow[i] * K + k0 + scg[i] * 8, sA + su[i] * 8);
      async_load16(Bg + (size_t)srow[i] * K + k0 + scg[i] * 8, sB + su[i] * 8);
    }
    __syncthreads();

    for (int ks = 0; ks < 2; ++ks) {
      bf16x8 af[4], bf[4];
      for (int t = 0; t < 4; ++t) {
        int mrow = wm + t * 16 + mm;
        int sa   = (ks * 4 + g) ^ (mrow & 7);
        af[t] = *(const bf16x8*)(sA + mrow * 64 + sa * 8);
        int nrow = wn + t * 16 + mm;
        int sb   = (ks * 4 + g) ^ (nrow & 7);
        bf[t] = *(const bf16x8*)(sB + nrow * 64 + sb * 8);
      }
      for (int tm = 0; tm < 4; ++tm)
        for (int tn = 0; tn < 4; ++tn)
          acc[tm][tn] = __builtin_amdgcn_mfma_f32_16x16x32_bf16(
              af[tm], bf[tn], acc[tm][tn], 0, 0, 0);
    }
    __syncthreads();
  }

  for (int tm = 0; tm < 4; ++tm) {
    int rowb = bm * 128 + wm + tm * 16 + g * 4;
    for (int tn = 0; tn < 4; ++tn) {
      int col = bn * 128 + wn + tn * 16 + mm;
      for (int r = 0; r < 4; ++r)
        C[(size_t)(rowb + r) * N + col] = acc[tm][tn][r];
    }
  }
}

// ---------------------------------------------------------------------------
extern "C" void kernel_launch(void* const* d_in, const int* in_sizes, int n_in,
                              void* d_out, int out_size, void* d_ws, size_t ws_size,
                              hipStream_t stream)
{
  const float* x   = (const float*)d_in[0];
  const int*   er0 = (const int*)d_in[1];
  const int*   ec0 = (const int*)d_in[2];
  const float* ev0 = (const float*)d_in[3];
  const int*   er1 = (const int*)d_in[4];
  const int*   ec1 = (const int*)d_in[5];
  const float* ev1 = (const float*)d_in[6];
  const int*   er2 = (const int*)d_in[7];
  const int*   ec2 = (const int*)d_in[8];
  const float* ev2 = (const float*)d_in[9];
  const int*   mr  = (const int*)d_in[10];
  const int*   mc  = (const int*)d_in[11];
  const float* mv  = (const float*)d_in[12];
  const int nnz_e0 = in_sizes[1];
  const int nnz_e1 = in_sizes[4];
  const int nnz_e2 = in_sizes[7];
  const int nnz_m  = in_sizes[10];

  int*   rp_all = (int*)d_ws;                              // 4*4096 ints
  int*   cc_all = rp_all + 4 * 4096;                       // 40960 ints used
  float* cv_all = (float*)(cc_all + 48 * 1024);            // 40960 floats used
  float* D      = (float*)(cv_all + 48 * 1024);            // [3*EROWS][F0] fp32 (12 MB)
  unsigned short* Mb = (unsigned short*)(D + (size_t)3 * EROWS * F0);  // 8 MB
  unsigned short* Ab = Mb + (size_t)NOUT * F0;             // 32 MB

  // 1) CSR-ize all four weights + cast x to bf16 (independent work, one node)
  hipLaunchKernelGGL(csr_cast_kernel, dim3(4 + 2048), dim3(256), 0, stream,
                     er0, ec0, ev0, nnz_e0,
                     er1, ec1, ev1, nnz_e1,
                     er2, ec2, ev2, nnz_e2,
                     mr,  mc,  mv,  nnz_m,
                     rp_all, cc_all, cv_all, x, Ab);

  // 2) expand chain (each launch depends on the previous -> stream order)
  hipLaunchKernelGGL((expand_csr_kernel<false>), dim3(EROWS), dim3(256), 0, stream,
                     rp_all + 0 * 4096, cc_all + 0 * 8192, cv_all + 0 * 8192,
                     D, (void*)D);
  hipLaunchKernelGGL((expand_csr_kernel<false>), dim3(EROWS), dim3(256), 0, stream,
                     rp_all + 1 * 4096, cc_all + 1 * 8192, cv_all + 1 * 8192,
                     D, (void*)(D + (size_t)EROWS * F0));
  hipLaunchKernelGGL((expand_csr_kernel<false>), dim3(EROWS), dim3(256), 0, stream,
                     rp_all + 2 * 4096, cc_all + 2 * 8192, cv_all + 2 * 8192,
                     D, (void*)(D + (size_t)2 * EROWS * F0));
  hipLaunchKernelGGL((expand_csr_kernel<true>), dim3(NOUT), dim3(256), 0, stream,
                     rp_all + 3 * 4096, cc_all + 3 * 8192, cv_all + 3 * 8192,
                     D, (void*)Mb);

  // 3) out = x @ M^T
  hipLaunchKernelGGL(gemm_bt_kernel, dim3(NOUT / 128, MROWS / 128), dim3(256),
                     0, stream, Ab, Mb, (float*)d_out);
}